// Round 2
// baseline (1219.081 us; speedup 1.0000x reference)
//
#include <hip/hip_runtime.h>
#include <stdint.h>

#define BATCH   8192
#define HALL    4096
#define TPB     256
#define PERT    (HALL / TPB)          // 16 items per thread
#define EPS     10
#define BH      33554432u             // BATCH*HALL = 8192*4096

// ---- JAX threefry2x32, key = (0, 42), constants folded -------------------
// Partitionable mode (jax_threefry_partitionable=True, default in modern JAX):
//   bits[L] = o0 ^ o1 where (o0,o1) = threefry2x32(key, (hi32(L), lo32(L)))
// and hi32(L) == 0 here since total draw count 335,544,320 < 2^32.
__device__ __forceinline__ uint32_t rotl32(uint32_t x, int r) {
    return (x << r) | (x >> (32 - r));   // compiles to v_alignbit_b32
}

__device__ __forceinline__ uint32_t threefry_bits_k42(uint32_t lo) {
    const uint32_t ks0 = 0u;
    const uint32_t ks1 = 42u;
    const uint32_t ks2 = 0x1BD11BDAu ^ 42u;
    uint32_t x0 = 0u + ks0;      // count hi word = 0
    uint32_t x1 = lo + ks1;      // count lo word = linear index
#define TF_R(r) { x0 += x1; x1 = rotl32(x1, r); x1 ^= x0; }
    TF_R(13) TF_R(15) TF_R(26) TF_R(6)   x0 += ks1; x1 += ks2 + 1u;
    TF_R(17) TF_R(29) TF_R(16) TF_R(24)  x0 += ks2; x1 += ks0 + 2u;
    TF_R(13) TF_R(15) TF_R(26) TF_R(6)   x0 += ks0; x1 += ks1 + 3u;
    TF_R(17) TF_R(29) TF_R(16) TF_R(24)  x0 += ks1; x1 += ks2 + 4u;
    TF_R(13) TF_R(15) TF_R(26) TF_R(6)   x0 += ks2; x1 += ks0 + 5u;
#undef TF_R
    return x0 ^ x1;              // 32-bit fold of the two output words
}

// ---- jax.random.uniform(minval=tiny, maxval=1) -> gumbel, op-for-op ------
__device__ __forceinline__ float gumbel_exact(uint32_t bits) {
    const float tiny = 1.1754943508222875e-38f;  // np.finfo(f32).tiny
    uint32_t fb = (bits >> 9) | 0x3F800000u;
    float f = __uint_as_float(fb) - 1.0f;        // [0, 1), exact
    float u = fmaxf(tiny, f * 1.0f + tiny);      // (maxval-minval) rounds to 1.0f
    float a = -logf(u);                          // -log(u) > 0
    return -logf(a);                             // gumbel = -log(-log(u))
}

// ---- block reductions (256 threads = 4 waves of 64) ----------------------
__device__ __forceinline__ float block_max(float v, float* swf, int tid) {
    for (int off = 32; off; off >>= 1)
        v = fmaxf(v, __shfl_down(v, off, 64));
    if ((tid & 63) == 0) swf[tid >> 6] = v;
    __syncthreads();
    float r = fmaxf(fmaxf(swf[0], swf[1]), fmaxf(swf[2], swf[3]));
    __syncthreads();
    return r;
}

__device__ __forceinline__ float block_sum(float v, float* swf, int tid) {
    for (int off = 32; off; off >>= 1)
        v += __shfl_down(v, off, 64);
    if ((tid & 63) == 0) swf[tid >> 6] = v;
    __syncthreads();
    float r = ((swf[0] + swf[1]) + swf[2]) + swf[3];
    __syncthreads();
    return r;
}

// argmax with first-index (lowest h) tie-break, matching jnp.argmax
__device__ __forceinline__ void block_argmax(float v, int i, float* swf, int* swi,
                                             int tid, float& rv, int& ri) {
    for (int off = 32; off; off >>= 1) {
        float ov = __shfl_down(v, off, 64);
        int   oi = __shfl_down(i, off, 64);
        if (ov > v || (ov == v && oi < i)) { v = ov; i = oi; }
    }
    if ((tid & 63) == 0) { swf[tid >> 6] = v; swi[tid >> 6] = i; }
    __syncthreads();
    rv = swf[0]; ri = swi[0];
#pragma unroll
    for (int w = 1; w < 4; w++) {
        float ov = swf[w]; int oi = swi[w];
        if (ov > rv || (ov == rv && oi < ri)) { rv = ov; ri = oi; }
    }
    __syncthreads();
}

// --------------------------------------------------------------------------
__global__ __launch_bounds__(TPB)
void reinforce_kernel(const float* __restrict__ X, const float* __restrict__ W,
                      const float* __restrict__ bias, int* __restrict__ out) {
#pragma clang fp contract(off)
    __shared__ float s_logp[HALL];
    __shared__ float swf[4];
    __shared__ int   swi[4];

    const int b   = blockIdx.x;
    const int tid = threadIdx.x;
    const float* xr = X + (size_t)b * (HALL * 3);

    // uniform scalar loads of W (3x3 row-major) and bias
    const float w00 = W[0], w01 = W[1], w02 = W[2], bb0 = bias[0];
    const float w10 = W[3], w11 = W[4], w12 = W[5], bb1 = bias[1];
    const float w20 = W[6], w21 = W[7], w22 = W[8], bb2 = bias[2];

    // ---- logits: thread owns h = tid + 256*j ; split: j<8 -> 0, j<12 -> 1, else 2
    float lg[PERT];
#pragma unroll
    for (int j = 0; j < PERT; j++) {
        int h = tid + j * TPB;
        float x0 = xr[3 * h], x1 = xr[3 * h + 1], x2 = xr[3 * h + 2];
        float wa, wb, wc, bb;
        if (j < 8)       { wa = w00; wb = w01; wc = w02; bb = bb0; }
        else if (j < 12) { wa = w10; wb = w11; wc = w12; bb = bb1; }
        else             { wa = w20; wb = w21; wc = w22; bb = bb2; }
        lg[j] = ((x0 * wa + x1 * wb) + x2 * wc) + bb;
    }

    // ---- per-split max
    float pm0 = -INFINITY, pm1 = -INFINITY, pm2 = -INFINITY;
#pragma unroll
    for (int j = 0; j < PERT; j++) {
        if (j < 8)       pm0 = fmaxf(pm0, lg[j]);
        else if (j < 12) pm1 = fmaxf(pm1, lg[j]);
        else             pm2 = fmaxf(pm2, lg[j]);
    }
    float m0 = block_max(pm0, swf, tid);
    float m1 = block_max(pm1, swf, tid);
    float m2 = block_max(pm2, swf, tid);

    // ---- per-split sum of exp(l - m)
    float ex[PERT];
    float ps0 = 0.f, ps1 = 0.f, ps2 = 0.f;
#pragma unroll
    for (int j = 0; j < PERT; j++) {
        float m = (j < 8) ? m0 : (j < 12) ? m1 : m2;
        float e = expf(lg[j] - m);
        ex[j] = e;
        if (j < 8)       ps0 += e;
        else if (j < 12) ps1 += e;
        else             ps2 += e;
    }
    float s0 = block_sum(ps0, swf, tid);
    float s1 = block_sum(ps1, swf, tid);
    float s2 = block_sum(ps2, swf, tid);

    // ---- p = exp/sum ; logp = log(p) (literal reference formula) ; best = argmax p
    float bv = -INFINITY; int bi = 0;
#pragma unroll
    for (int j = 0; j < PERT; j++) {
        float s = (j < 8) ? s0 : (j < 12) ? s1 : s2;
        float p = ex[j] / s;
        int h = tid + j * TPB;
        if (p > bv) { bv = p; bi = h; }   // ascending h => strict > keeps first idx
        s_logp[h] = logf(p);
    }
    __syncthreads();   // s_logp complete before sampling reads

    float rbv; int best;
    block_argmax(bv, bi, swf, swi, tid, rbv, best);

    // ---- epsilon sampling: gumbel(e,b,h) + logp, argmax over h, 10 eps
    // linear index of (e,b,h) in the (10, 8192, 4096) gumbel tensor:
    //   L = e*BH + b*HALL + h   (fits in uint32)
    float sv[EPS]; int si[EPS];
#pragma unroll
    for (int e = 0; e < EPS; e++) { sv[e] = -INFINITY; si[e] = 0x7fffffff; }

    const uint32_t rowbase = (uint32_t)b * (uint32_t)HALL;
    for (int j = 0; j < PERT; j++) {
        int h = tid + j * TPB;
        float lp = s_logp[h];
        uint32_t cnt = rowbase + (uint32_t)h;
#pragma unroll
        for (int e = 0; e < EPS; e++) {
            uint32_t bits = threefry_bits_k42(cnt + (uint32_t)e * BH);
            float v = gumbel_exact(bits) + lp;
            if (v > sv[e]) { sv[e] = v; si[e] = h; }
        }
    }

    int samp[EPS];
#pragma unroll
    for (int e = 0; e < EPS; e++) {
        float rv; int ri;
        block_argmax(sv[e], si[e], swf, swi, tid, rv, ri);
        samp[e] = ri;
    }

    if (tid == 0) {
        bool hit = false;
#pragma unroll
        for (int e = 0; e < EPS; e++) hit = hit || (samp[e] == best);
        out[b] = hit ? best : samp[EPS - 1];
    }
}

extern "C" void kernel_launch(void* const* d_in, const int* in_sizes, int n_in,
                              void* d_out, int out_size, void* d_ws, size_t ws_size,
                              hipStream_t stream) {
    const float* X    = (const float*)d_in[0];   // (8192, 12288) f32
    const float* W    = (const float*)d_in[1];   // (3, 3) f32
    const float* bias = (const float*)d_in[2];   // (3,) f32
    int* out = (int*)d_out;                      // (8192,) int32 actions
    (void)in_sizes; (void)n_in; (void)d_ws; (void)ws_size; (void)out_size;

    reinforce_kernel<<<BATCH, TPB, 0, stream>>>(X, W, bias, out);
}

// Round 3
// 1132.408 us; speedup vs baseline: 1.0765x; 1.0765x over previous
//
#include <hip/hip_runtime.h>
#include <stdint.h>

#define BATCH   8192
#define HALL    4096
#define TPB     256
#define PERT    16                    // HALL / TPB items per thread
#define EPS     10
#define BH      33554432u             // BATCH*HALL

// ---- JAX threefry2x32, partitionable mode, key = (0, 42) -----------------
// bits[L] = o0 ^ o1, (o0,o1) = threefry2x32(key, (0, L)); L < 2^32 here.
__device__ __forceinline__ uint32_t rotl32(uint32_t x, int r) {
    return (x << r) | (x >> (32 - r));   // v_alignbit_b32
}

__device__ __forceinline__ uint32_t threefry_bits_k42(uint32_t lo) {
    const uint32_t ks0 = 0u;
    const uint32_t ks1 = 42u;
    const uint32_t ks2 = 0x1BD11BDAu ^ 42u;
    uint32_t x0 = 0u + ks0;
    uint32_t x1 = lo + ks1;
#define TF_R(r) { x0 += x1; x1 = rotl32(x1, r); x1 ^= x0; }
    TF_R(13) TF_R(15) TF_R(26) TF_R(6)   x0 += ks1; x1 += ks2 + 1u;
    TF_R(17) TF_R(29) TF_R(16) TF_R(24)  x0 += ks2; x1 += ks0 + 2u;
    TF_R(13) TF_R(15) TF_R(26) TF_R(6)   x0 += ks0; x1 += ks1 + 3u;
    TF_R(17) TF_R(29) TF_R(16) TF_R(24)  x0 += ks1; x1 += ks2 + 4u;
    TF_R(13) TF_R(15) TF_R(26) TF_R(6)   x0 += ks2; x1 += ks0 + 5u;
#undef TF_R
    return x0 ^ x1;
}

// --------------------------------------------------------------------------
__global__ __launch_bounds__(TPB)
void reinforce_kernel(const float* __restrict__ X, const float* __restrict__ W,
                      const float* __restrict__ bias, int* __restrict__ out) {
#pragma clang fp contract(off)
    __shared__ float s_p[HALL];       // per-item softmax prob (own-thread use)
    __shared__ float s_rm[3][4];      // per-split max, per wave
    __shared__ float s_rs[3][4];      // per-split sum, per wave
    __shared__ float s_rv[EPS + 1][4];// tail: 10 eps ratios + best-p, per wave
    __shared__ int   s_ri[EPS + 1][4];

    const int b   = blockIdx.x;
    const int tid = threadIdx.x;
    const int wv  = tid >> 6;
    const int ln  = tid & 63;
    const float* xr = X + (size_t)b * (HALL * 3);

    const float w00 = W[0], w01 = W[1], w02 = W[2], bb0 = bias[0];
    const float w10 = W[3], w11 = W[4], w12 = W[5], bb1 = bias[1];
    const float w20 = W[6], w21 = W[7], w22 = W[8], bb2 = bias[2];

    // ---- logits: thread owns h = tid + 256*j ; split: j<8 ->0, j<12 ->1, else 2
    float lg[PERT];
#pragma unroll
    for (int j = 0; j < PERT; j++) {
        int h = tid + j * TPB;
        float x0 = xr[3 * h], x1 = xr[3 * h + 1], x2 = xr[3 * h + 2];
        float wa, wb, wc, bb;
        if (j < 8)       { wa = w00; wb = w01; wc = w02; bb = bb0; }
        else if (j < 12) { wa = w10; wb = w11; wc = w12; bb = bb1; }
        else             { wa = w20; wb = w21; wc = w22; bb = bb2; }
        lg[j] = ((x0 * wa + x1 * wb) + x2 * wc) + bb;
    }

    // ---- per-split max (fused 3-value wave reduce, 1 sync)
    float pm0 = -INFINITY, pm1 = -INFINITY, pm2 = -INFINITY;
#pragma unroll
    for (int j = 0; j < PERT; j++) {
        if (j < 8)       pm0 = fmaxf(pm0, lg[j]);
        else if (j < 12) pm1 = fmaxf(pm1, lg[j]);
        else             pm2 = fmaxf(pm2, lg[j]);
    }
    for (int off = 32; off; off >>= 1) {
        pm0 = fmaxf(pm0, __shfl_down(pm0, off, 64));
        pm1 = fmaxf(pm1, __shfl_down(pm1, off, 64));
        pm2 = fmaxf(pm2, __shfl_down(pm2, off, 64));
    }
    if (ln == 0) { s_rm[0][wv] = pm0; s_rm[1][wv] = pm1; s_rm[2][wv] = pm2; }
    __syncthreads();
    const float m0 = fmaxf(fmaxf(s_rm[0][0], s_rm[0][1]), fmaxf(s_rm[0][2], s_rm[0][3]));
    const float m1 = fmaxf(fmaxf(s_rm[1][0], s_rm[1][1]), fmaxf(s_rm[1][2], s_rm[1][3]));
    const float m2 = fmaxf(fmaxf(s_rm[2][0], s_rm[2][1]), fmaxf(s_rm[2][2], s_rm[2][3]));

    // ---- per-split sum of exp(l - m) (fused 3-value wave reduce, 1 sync)
    float ex[PERT];
    float ps0 = 0.f, ps1 = 0.f, ps2 = 0.f;
#pragma unroll
    for (int j = 0; j < PERT; j++) {
        float m = (j < 8) ? m0 : (j < 12) ? m1 : m2;
        float e = expf(lg[j] - m);
        ex[j] = e;
        if (j < 8)       ps0 += e;
        else if (j < 12) ps1 += e;
        else             ps2 += e;
    }
    for (int off = 32; off; off >>= 1) {
        ps0 += __shfl_down(ps0, off, 64);
        ps1 += __shfl_down(ps1, off, 64);
        ps2 += __shfl_down(ps2, off, 64);
    }
    if (ln == 0) { s_rs[0][wv] = ps0; s_rs[1][wv] = ps1; s_rs[2][wv] = ps2; }
    __syncthreads();
    const float s0 = ((s_rs[0][0] + s_rs[0][1]) + s_rs[0][2]) + s_rs[0][3];
    const float s1 = ((s_rs[1][0] + s_rs[1][1]) + s_rs[1][2]) + s_rs[1][3];
    const float s2 = ((s_rs[2][0] + s_rs[2][1]) + s_rs[2][2]) + s_rs[2][3];

    // ---- p = ex/s ; best = argmax p ; stash p in LDS (read back by same thread)
    float bv = -INFINITY; int bi = 0;
#pragma unroll
    for (int j = 0; j < PERT; j++) {
        float s = (j < 8) ? s0 : (j < 12) ? s1 : s2;
        float p = ex[j] / s;
        int h = tid + j * TPB;
        if (p > bv) { bv = p; bi = h; }   // ascending h => strict > keeps first idx
        s_p[h] = p;                        // own-thread store; no sync needed
    }

    // ---- epsilon sampling in transformed space:
    // argmax_h( logp + (-log(-log u)) )  ==  argmax_h( p / a ),  a = -log(u) > 0
    // running max kept as (pm, am, idx); candidate wins iff p*am > pm*a.
    const float tiny = 1.1754943508222875e-38f;
    float apv[EPS]; float aav[EPS]; int aix[EPS];
#pragma unroll
    for (int e = 0; e < EPS; e++) { apv[e] = 0.0f; aav[e] = 1.0f; aix[e] = 0x7fffffff; }

    const uint32_t rowbase = (uint32_t)b * (uint32_t)HALL;
#pragma unroll 1
    for (int j = 0; j < PERT; j++) {
        int h = tid + j * TPB;
        float pj = s_p[h];                 // ds_read of own element
        uint32_t cnt = rowbase + (uint32_t)h;
#pragma unroll
        for (int e = 0; e < EPS; e++) {
            uint32_t bits = threefry_bits_k42(cnt + (uint32_t)e * BH);
            uint32_t fb = (bits >> 9) | 0x3F800000u;
            float f = __uint_as_float(fb) - 1.0f;   // [0,1), multiple of 2^-23
            float u = fmaxf(f, tiny);               // == fl(f*1+tiny) bit-exact
            float a = -logf(u);                     // accurate log (u~1 critical)
            if (pj * aav[e] > apv[e] * a) { apv[e] = pj; aav[e] = a; aix[e] = h; }
        }
    }

    // ---- tail: wave-reduce 10 eps (r = p/a, idx) + best (p, idx); ONE sync
#pragma unroll
    for (int e = 0; e < EPS; e++) {
        float r = apv[e] / aav[e];
        int   i = aix[e];
        for (int off = 32; off; off >>= 1) {
            float rv = __shfl_down(r, off, 64);
            int   ri = __shfl_down(i, off, 64);
            if (rv > r || (rv == r && ri < i)) { r = rv; i = ri; }
        }
        if (ln == 0) { s_rv[e][wv] = r; s_ri[e][wv] = i; }
    }
    {
        float r = bv; int i = bi;
        for (int off = 32; off; off >>= 1) {
            float rv = __shfl_down(r, off, 64);
            int   ri = __shfl_down(i, off, 64);
            if (rv > r || (rv == r && ri < i)) { r = rv; i = ri; }
        }
        if (ln == 0) { s_rv[EPS][wv] = r; s_ri[EPS][wv] = i; }
    }
    __syncthreads();

    if (tid == 0) {
        int samp[EPS];
#pragma unroll
        for (int e = 0; e <= EPS; e++) {
            float r = s_rv[e][0]; int i = s_ri[e][0];
#pragma unroll
            for (int w = 1; w < 4; w++) {
                float rv = s_rv[e][w]; int ri = s_ri[e][w];
                if (rv > r || (rv == r && ri < i)) { r = rv; i = ri; }
            }
            if (e < EPS) samp[e] = i;
            else {
                int best = i;
                bool hit = false;
#pragma unroll
                for (int k = 0; k < EPS; k++) hit = hit || (samp[k] == best);
                out[b] = hit ? best : samp[EPS - 1];
            }
        }
    }
}

extern "C" void kernel_launch(void* const* d_in, const int* in_sizes, int n_in,
                              void* d_out, int out_size, void* d_ws, size_t ws_size,
                              hipStream_t stream) {
    const float* X    = (const float*)d_in[0];   // (8192, 12288) f32
    const float* W    = (const float*)d_in[1];   // (3, 3) f32
    const float* bias = (const float*)d_in[2];   // (3,) f32
    int* out = (int*)d_out;                      // (8192,) int32 actions
    (void)in_sizes; (void)n_in; (void)d_ws; (void)ws_size; (void)out_size;

    reinforce_kernel<<<BATCH, TPB, 0, stream>>>(X, W, bias, out);
}